// Round 17
// baseline (96.861 us; speedup 1.0000x reference)
//
#include <hip/hip_runtime.h>

// Problem constants
#define MD 4
#define PATCH 9          // 2*MD+1
#define NBAND 256        // band-compute blocks: (b, ty) = 4 * 64
#define NZERO 1024       // zero-streaming blocks
#define BT 1024          // threads per block (16 waves)
// feat1/feat2: (4, 256, 64, 64) fp32
// out: (4, 4096, 64, 64) fp32 = 256 MB
//
// out[b, ty*64+tx, y, x] = sum_c f1[b,c,y,x] * f2[b,c,ty,tx]  if |ty-y|<=4 && |tx-x|<=4, else 0.
//
// R17 = R16's bf16-pair LDS window + two f1-stall fixes (R16 falsified the LDS-issue
// theory; R13/R15 falsified low-MLP and spill directions -> band is f1-load-bound):
//   1) dual-stream pairs (cp, cp+16) per iteration -> 8 batched global loads in flight
//      per wave-iter (2x R16), still under the 64-VGPR cap (bf16 window = 9 regs).
//   2) XCD swizzle of band blocks: bty = (bid&7)*32 + (bid>>3) -> each XCD's L2 keeps
//      the f1 rows shared by its 32 consecutive ty -> ty-neighbor re-reads hit L2.
// 16-wave blocks (cq quarter x dyg), bf16 precision on f2 only (R16 absmax 0.5 << 1.6).

__device__ __forceinline__ unsigned bf16b(float x)   // f32 -> bf16 bits (RNE)
{
    unsigned u = __float_as_uint(x);
    return (u + 0x7fffu + ((u >> 16) & 1u)) >> 16;
}

// Dual-stream core (nd=2 waves): pairs cp and cp+16 of this wave's 32-pair range.
__device__ __forceinline__ void band_core_dual(
    const float* __restrict__ f1base,          // f1 + (b*256 + cq*64)*4096 + lane
    const unsigned (* __restrict__ sw)[72],    // sF2 + cq*32 pair-rows
    int ty, int dy0, int lane,
    float acc[3][PATCH])
{
    int yoff[2];
#pragma unroll
    for (int i = 0; i < 2; ++i) {
        int y = ty + dy0 + i - MD;
        y = y < 0 ? 0 : (y > 63 ? 63 : y);
        yoff[i] = y * 64;
    }

    for (int cp = 0; cp < 16; ++cp) {
        const float* cA = f1base + (size_t)(2 * cp) * 4096;        // channels 2cp, 2cp+1
        const float* cB = cA + (size_t)32 * 4096;                  // channels 2cp+32, +33
        float a0[2], a1[2], b0[2], b1[2];
#pragma unroll
        for (int i = 0; i < 2; ++i) {                              // 8 batched loads
            a0[i] = cA[yoff[i]];
            a1[i] = cA[4096 + yoff[i]];
            b0[i] = cB[yoff[i]];
            b1[i] = cB[4096 + yoff[i]];
        }
        const unsigned* wA = &sw[cp][lane];
        const unsigned* wB = &sw[cp + 16][lane];
        unsigned shA[PATCH], shB[PATCH];
#pragma unroll
        for (int dxi = 0; dxi < PATCH; ++dxi) {
            shA[dxi] = wA[8 - dxi];                                // 18 ds_read_b32, 4 ch each pair
            shB[dxi] = wB[8 - dxi];
        }
#pragma unroll
        for (int dxi = 0; dxi < PATCH; ++dxi) {
            float loA = __uint_as_float(shA[dxi] << 16);
            float hiA = __uint_as_float(shA[dxi] & 0xffff0000u);
            float loB = __uint_as_float(shB[dxi] << 16);
            float hiB = __uint_as_float(shB[dxi] & 0xffff0000u);
#pragma unroll
            for (int i = 0; i < 2; ++i) {
                acc[i][dxi] = fmaf(a0[i], loA, acc[i][dxi]);
                acc[i][dxi] = fmaf(a1[i], hiA, acc[i][dxi]);
                acc[i][dxi] = fmaf(b0[i], loB, acc[i][dxi]);
                acc[i][dxi] = fmaf(b1[i], hiB, acc[i][dxi]);
            }
        }
    }
}

// Single-stream core (the nd=3 wave): 32 pairs, unroll 2 (R16 shape; dual would spill).
__device__ __forceinline__ void band_core3(
    const float* __restrict__ f1base,
    const unsigned (* __restrict__ sw)[72],
    int ty, int dy0, int lane,
    float acc[3][PATCH])
{
    int yoff[3];
#pragma unroll
    for (int i = 0; i < 3; ++i) {
        int y = ty + dy0 + i - MD;
        y = y < 0 ? 0 : (y > 63 ? 63 : y);
        yoff[i] = y * 64;
    }

#pragma unroll 2
    for (int cp = 0; cp < 32; ++cp) {
        const float* c0 = f1base + (size_t)(2 * cp) * 4096;
        float f1v0[3], f1v1[3];
#pragma unroll
        for (int i = 0; i < 3; ++i) {
            f1v0[i] = c0[yoff[i]];
            f1v1[i] = c0[4096 + yoff[i]];
        }
        const unsigned* wp = &sw[cp][lane];
        unsigned sh2[PATCH];
#pragma unroll
        for (int dxi = 0; dxi < PATCH; ++dxi)
            sh2[dxi] = wp[8 - dxi];
#pragma unroll
        for (int dxi = 0; dxi < PATCH; ++dxi) {
            float lo = __uint_as_float(sh2[dxi] << 16);
            float hi = __uint_as_float(sh2[dxi] & 0xffff0000u);
#pragma unroll
            for (int i = 0; i < 3; ++i) {
                acc[i][dxi] = fmaf(f1v0[i], lo, acc[i][dxi]);
                acc[i][dxi] = fmaf(f1v1[i], hi, acc[i][dxi]);
            }
        }
    }
}

__global__ __launch_bounds__(BT, 8) void cv_kernel(
    const float* __restrict__ f1,
    const float* __restrict__ f2,
    float* __restrict__ out)
{
    const int tid = threadIdx.x;

    // ---------------- zero-streaming blocks ----------------
    if (blockIdx.x >= NBAND) {
        // float4 index i: bits [0:4)=x4, [4:10)=y, [10:16)=tx, [16:22)=ty, [22:24)=b
        float4* o4 = (float4*)out;
        const float4 z4 = make_float4(0.f, 0.f, 0.f, 0.f);
        const int total4 = 4 * 4096 * 64 * 16;            // 16,777,216
        const int stride = NZERO * BT;
        for (int i = (blockIdx.x - NBAND) * BT + tid; i < total4; i += stride) {
            int y  = (i >> 4) & 63;
            int ty = (i >> 16) & 63;
            int dy = y - ty;
            if (dy < -MD || dy > MD)
                o4[i] = z4;
        }
        return;
    }

    // ---------------- band-compute blocks ----------------
    // XCD swizzle: consecutive (b,ty) land on the SAME XCD so its L2 keeps the shared
    // f1 row window (assumes round-robin workgroup->XCD; worst case = noise).
    const int bid = blockIdx.x;           // 0..255
    const int bty = ((bid & 7) << 5) | (bid >> 3);
    const int b   = bty >> 6;
    const int ty  = bty & 63;
    const int lane = tid & 63;            // u = x position
    const int w    = tid >> 6;            // 0..15
    const int cq   = w >> 2;              // channel quarter (64 ch = 32 pairs)
    const int dyg  = w & 3;               // dy group: rows {0,1}/{2,3}/{4,5}/{6,7,8}
    const int dy0  = dyg * 2;
    const int nd   = (dyg == 3) ? 3 : 2;

    __shared__ unsigned uLds[128 * 72];   // 36,864 B: sF2[128][72] u32 bf16-pairs, sVals after
    unsigned (*sF2)[72] = (unsigned(*)[72])uLds;

    // zero the 4-slot margins: p in {0,1,2,3,68,69,70,71} per pair-row
    {
        int c2 = tid >> 3, s = tid & 7;
        sF2[c2][s < 4 ? s : 64 + s] = 0u;
    }
    // main staging: e -> c2 = e>>6 (pair row), x = e&63; coalesced f32 reads, u32 writes
    const float* f2b = f2 + (size_t)(b * 256) * 4096 + ty * 64;
#pragma unroll
    for (int m = 0; m < 8; ++m) {
        int e  = m * BT + tid;            // 0..8191
        int c2 = e >> 6, x = e & 63;
        float lo = f2b[(size_t)(2 * c2) * 4096 + x];
        float hi = f2b[(size_t)(2 * c2 + 1) * 4096 + x];
        sF2[c2][4 + x] = (bf16b(hi) << 16) | bf16b(lo);
    }
    __syncthreads();

    float acc[3][PATCH];
#pragma unroll
    for (int i = 0; i < 3; ++i)
#pragma unroll
        for (int j = 0; j < PATCH; ++j) acc[i][j] = 0.f;

    const float* f1b = f1 + (size_t)(b * 256 + cq * 64) * 4096 + lane;
    const unsigned (*sw)[72] = &sF2[cq * 32];

    if (dyg == 3) band_core3(f1b, sw, ty, dy0, lane, acc);
    else          band_core_dual(f1b, sw, ty, dy0, lane, acc);

    __syncthreads();                      // all sF2 reads complete; uLds becomes sVals
    float (*sVals)[81] = (float(*)[81])uLds;   // sVals[tx][dyi*9+dxi]

    // Merge without zero-fill: cq==0 waves cover every read entry exactly once -> store.
    if (cq == 0) {
#pragma unroll
        for (int i = 0; i < 3; ++i) {
            if (i >= nd) continue;        // wave-uniform
            int dyi = dy0 + i;
            int y = ty + dyi - MD;
            if ((unsigned)y >= 64u) continue;
#pragma unroll
            for (int dxi = 0; dxi < PATCH; ++dxi) {
                int tx = lane - (dxi - MD);
                if ((unsigned)tx < 64u)
                    sVals[tx][dyi * PATCH + dxi] = acc[i][dxi];   // stride 81: conflict-free
            }
        }
    }
    __syncthreads();
    if (cq != 0) {
#pragma unroll
        for (int i = 0; i < 3; ++i) {
            if (i >= nd) continue;
            int dyi = dy0 + i;
            int y = ty + dyi - MD;
            if ((unsigned)y >= 64u) continue;
#pragma unroll
            for (int dxi = 0; dxi < PATCH; ++dxi) {
                int tx = lane - (dxi - MD);
                if ((unsigned)tx < 64u)
                    atomicAdd(&sVals[tx][dyi * PATCH + dxi], acc[i][dxi]);
            }
        }
    }
    __syncthreads();

    // Band rows: full 64-float rows (9-wide value window, zeros elsewhere).
    float4* out4 = (float4*)(out + (size_t)(b * 4096 + ty * 64) * 4096);
    const int q4 = tid & 15;              // float4 index within a row
    const int ro = tid >> 4;              // 0..63
    for (int rb = 0; rb < 64 * PATCH; rb += 64) {
        int row = rb + ro;                // row = tx*9 + dyi
        int tx  = row / PATCH;            // const divisor -> magic multiply
        int dyi = row - tx * PATCH;
        int y   = ty + dyi - MD;
        if ((unsigned)y < 64u) {
            float comp[4];
#pragma unroll
            for (int j = 0; j < 4; ++j) {
                int x  = q4 * 4 + j;
                int dx = x - tx;
                comp[j] = (dx >= -MD && dx <= MD) ? sVals[tx][dyi * PATCH + dx + MD] : 0.f;
            }
            out4[tx * 1024 + y * 16 + q4] = make_float4(comp[0], comp[1], comp[2], comp[3]);
        }
    }
}

extern "C" void kernel_launch(void* const* d_in, const int* in_sizes, int n_in,
                              void* d_out, int out_size, void* d_ws, size_t ws_size,
                              hipStream_t stream) {
    const float* f1 = (const float*)d_in[0];
    const float* f2 = (const float*)d_in[1];
    float* out = (float*)d_out;
    cv_kernel<<<NBAND + NZERO, BT, 0, stream>>>(f1, f2, out);
}

// Round 18
// 93.106 us; speedup vs baseline: 1.0403x; 1.0403x over previous
//
#include <hip/hip_runtime.h>

// Problem constants
#define MD 4
#define PATCH 9          // 2*MD+1
#define NBAND 512        // band blocks: (b, ty, dy-half) = 4 * 64 * 2
#define NZERO 2048       // zero-streaming blocks
#define BT 512           // threads per block (8 waves)
// feat1/feat2: (4, 256, 64, 64) fp32
// out: (4, 4096, 64, 64) fp32 = 256 MB
//
// out[b, ty*64+tx, y, x] = sum_c f1[b,c,y,x] * f2[b,c,ty,tx]  if |ty-y|<=4 && |tx-x|<=4, else 0.
//
// R18 = R16 (85.9us; bf16-pair LDS window, 512-thr blocks) with ONE change: each (b,ty)'s
// band work is split across TWO blocks by dy-half (rows 0-3 / 4-8) -> 512 band blocks,
// 2 independent band blocks per CU. R11/R16's invariant 55us band phase (insensitive to
// inner-loop structure) points to the block-wide stage->barrier->compute->vmcnt(0)-drain
// critical path with NO independent co-resident band work to hide it; two blocks/CU let
// one block's waves issue while the other drains. Per-CU band work unchanged; f2 staged
// twice per (b,ty) (trivial +64KB). Zero stream, merge, writeout: R16-verbatim.

__device__ __forceinline__ unsigned bf16b(float x)   // f32 -> bf16 bits (RNE)
{
    unsigned u = __float_as_uint(x);
    return (u + 0x7fffu + ((u >> 16) & 1u)) >> 16;
}

template<int ND>
__device__ __forceinline__ void band_core(
    const float* __restrict__ f1base,          // f1 + (b*256 + cq*64)*4096 + lane
    const unsigned (* __restrict__ sw)[72],    // this wave's 32 padded channel-pair rows
    int ty, int dy0, int lane,
    float acc[3][PATCH])
{
    int yoff[ND];                          // clamped; invalid rows discarded at merge
#pragma unroll
    for (int i = 0; i < ND; ++i) {
        int y = ty + dy0 + i - MD;
        y = y < 0 ? 0 : (y > 63 ? 63 : y);
        yoff[i] = y * 64;
    }

#pragma unroll 2
    for (int cp = 0; cp < 32; ++cp) {      // channel pair: channels 2cp, 2cp+1 of this quarter
        const float* c0 = f1base + (size_t)(2 * cp) * 4096;
        float f1v0[ND], f1v1[ND];
#pragma unroll
        for (int i = 0; i < ND; ++i) {
            f1v0[i] = c0[yoff[i]];                    // batched coalesced global loads
            f1v1[i] = c0[4096 + yoff[i]];
        }
        const unsigned* wp = &sw[cp][lane];
        unsigned sh2[PATCH];
#pragma unroll
        for (int dxi = 0; dxi < PATCH; ++dxi)
            sh2[dxi] = wp[8 - dxi];                   // ds_read_b32: 2 channels per read
#pragma unroll
        for (int dxi = 0; dxi < PATCH; ++dxi) {
            float lo = __uint_as_float(sh2[dxi] << 16);          // channel 2cp
            float hi = __uint_as_float(sh2[dxi] & 0xffff0000u);  // channel 2cp+1
#pragma unroll
            for (int i = 0; i < ND; ++i) {
                acc[i][dxi] = fmaf(f1v0[i], lo, acc[i][dxi]);
                acc[i][dxi] = fmaf(f1v1[i], hi, acc[i][dxi]);
            }
        }
    }
}

__global__ __launch_bounds__(BT, 8) void cv_kernel(
    const float* __restrict__ f1,
    const float* __restrict__ f2,
    float* __restrict__ out)
{
    const int tid = threadIdx.x;

    // ---------------- zero-streaming blocks ----------------
    if (blockIdx.x >= NBAND) {
        // float4 index i: bits [0:4)=x4, [4:10)=y, [10:16)=tx, [16:22)=ty, [22:24)=b
        float4* o4 = (float4*)out;
        const float4 z4 = make_float4(0.f, 0.f, 0.f, 0.f);
        const int total4 = 4 * 4096 * 64 * 16;            // 16,777,216
        const int stride = NZERO * BT;
        for (int i = (blockIdx.x - NBAND) * BT + tid; i < total4; i += stride) {
            int y  = (i >> 4) & 63;
            int ty = (i >> 16) & 63;
            int dy = y - ty;
            if (dy < -MD || dy > MD)
                o4[i] = z4;
        }
        return;
    }

    // ---------------- band-compute blocks ----------------
    const int bb   = blockIdx.x;      // 0..511
    const int bty  = bb >> 1;         // 0..255
    const int half = bb & 1;          // 0 -> dyi 0..3, 1 -> dyi 4..8
    const int b    = bty >> 6;
    const int ty   = bty & 63;
    const int lane = tid & 63;        // u = x position
    const int w    = tid >> 6;        // 0..7
    const int cq   = w >> 1;          // channel quarter (64 ch = 32 pairs)
    const int dh   = w & 1;           // dy sub-group within the half
    const int dy0  = half * 4 + dh * 2;
    const int nd   = (half && dh) ? 3 : 2;   // rows {0,1}/{2,3}/{4,5}/{6,7,8}

    __shared__ unsigned uLds[128 * 72];    // 36,864 B: sF2[128][72] u32 bf16-pairs, sVals after
    unsigned (*sF2)[72] = (unsigned(*)[72])uLds;

    // zero the 4-slot margins: p in {0,1,2,3,68,69,70,71} per pair-row
    for (int i = tid; i < 128 * 8; i += BT) {
        int c2 = i >> 3, s = i & 7;
        sF2[c2][s < 4 ? s : 64 + s] = 0u;
    }
    // main staging: e -> c2 = e>>6 (pair row), x = e&63; coalesced f32 reads, u32 writes
    const float* f2b = f2 + (size_t)(b * 256) * 4096 + ty * 64;
#pragma unroll
    for (int m = 0; m < 16; ++m) {
        int e  = m * BT + tid;        // 0..8191
        int c2 = e >> 6, x = e & 63;
        float lo = f2b[(size_t)(2 * c2) * 4096 + x];
        float hi = f2b[(size_t)(2 * c2 + 1) * 4096 + x];
        sF2[c2][4 + x] = (bf16b(hi) << 16) | bf16b(lo);
    }
    __syncthreads();

    float acc[3][PATCH];
#pragma unroll
    for (int i = 0; i < 3; ++i)
#pragma unroll
        for (int j = 0; j < PATCH; ++j) acc[i][j] = 0.f;

    const float* f1b = f1 + (size_t)(b * 256 + cq * 64) * 4096 + lane;
    const unsigned (*sw)[72] = &sF2[cq * 32];

    if (nd == 3) band_core<3>(f1b, sw, ty, dy0, lane, acc);
    else         band_core<2>(f1b, sw, ty, dy0, lane, acc);

    __syncthreads();                  // all sF2 reads complete; uLds becomes sVals
    float (*sVals)[81] = (float(*)[81])uLds;   // sVals[tx][dyi*9+dxi]

    // Merge without zero-fill: cq==0 waves cover this half's entries exactly once -> store.
    if (cq == 0) {
#pragma unroll
        for (int i = 0; i < 3; ++i) {
            if (i >= nd) continue;    // wave-uniform
            int dyi = dy0 + i;
            int y = ty + dyi - MD;
            if ((unsigned)y >= 64u) continue;
#pragma unroll
            for (int dxi = 0; dxi < PATCH; ++dxi) {
                int tx = lane - (dxi - MD);
                if ((unsigned)tx < 64u)
                    sVals[tx][dyi * PATCH + dxi] = acc[i][dxi];   // stride 81: conflict-free
            }
        }
    }
    __syncthreads();
    if (cq != 0) {
#pragma unroll
        for (int i = 0; i < 3; ++i) {
            if (i >= nd) continue;
            int dyi = dy0 + i;
            int y = ty + dyi - MD;
            if ((unsigned)y >= 64u) continue;
#pragma unroll
            for (int dxi = 0; dxi < PATCH; ++dxi) {
                int tx = lane - (dxi - MD);
                if ((unsigned)tx < 64u)
                    atomicAdd(&sVals[tx][dyi * PATCH + dxi], acc[i][dxi]);
            }
        }
    }
    __syncthreads();

    // Writeout: this half's rows (4 or 5 dyi), full 64-float rows, coalesced float4.
    float4* out4 = (float4*)(out + (size_t)(b * 4096 + ty * 64) * 4096);
    const int q4 = tid & 15;          // float4 index within a row
    const int ro = tid >> 4;          // 0..31
    const int NR = half ? 5 : 4;
    const int DY0 = half * 4;
    for (int rb = 0; rb < 64 * NR; rb += 32) {
        int row = rb + ro;            // row = tx*NR + (dyi-DY0)
        int tx, dyi;
        if (!half) { tx = row >> 2; dyi = row & 3; }
        else       { tx = row / 5;  dyi = DY0 + (row - 5 * tx); }
        int y = ty + dyi - MD;
        if ((unsigned)y < 64u) {
            float comp[4];
#pragma unroll
            for (int j = 0; j < 4; ++j) {
                int x  = q4 * 4 + j;
                int dx = x - tx;
                comp[j] = (dx >= -MD && dx <= MD) ? sVals[tx][dyi * PATCH + dx + MD] : 0.f;
            }
            out4[tx * 1024 + y * 16 + q4] = make_float4(comp[0], comp[1], comp[2], comp[3]);
        }
    }
}

extern "C" void kernel_launch(void* const* d_in, const int* in_sizes, int n_in,
                              void* d_out, int out_size, void* d_ws, size_t ws_size,
                              hipStream_t stream) {
    const float* f1 = (const float*)d_in[0];
    const float* f2 = (const float*)d_in[1];
    float* out = (float*)d_out;
    cv_kernel<<<NBAND + NZERO, BT, 0, stream>>>(f1, f2, out);
}

// Round 19
// 85.982 us; speedup vs baseline: 1.1265x; 1.0829x over previous
//
#include <hip/hip_runtime.h>

// Problem constants
#define MD 4
#define PATCH 9          // 2*MD+1
#define NBAND 256        // band-compute blocks: (b, ty) = 4 * 64
#define NZERO 2048       // zero-streaming blocks
#define BT 512           // threads per block (8 waves)
// feat1/feat2: (4, 256, 64, 64) fp32
// out: (4, 4096, 64, 64) fp32 = 256 MB
//
// out[b, ty*64+tx, y, x] = sum_c f1[b,c,y,x] * f2[b,c,ty,tx]  if |ty-y|<=4 && |tx-x|<=4, else 0.
//
// R19 = R16 (85.9us best-family; bf16-pair LDS window, 512-thr blocks) + ONE mechanism:
// keep f1 L2-resident across its 9x ty-overlap re-reads (FETCH=72MB ~= 2x inputs showed
// the re-reads missing):
//   1) XCD swizzle of band blocks: bty = (bid&7)*32 + (bid>>3) -> each XCD's L2 holds
//      the 2.6 MB f1 row window shared by its 32 consecutive (b,ty).
//   2) nontemporal stores for ALL output writes (zero stream + band writeout): the
//      220 MB write stream must not evict f1 from L2 (output is write-once, never read).
// Inner loop, staging, merge, writeout indexing: R16-verbatim.

typedef float f4v __attribute__((ext_vector_type(4)));

__device__ __forceinline__ void nt_store4(float* p, float a, float b, float c, float d)
{
    f4v v = {a, b, c, d};
    __builtin_nontemporal_store(v, (f4v*)p);
}

__device__ __forceinline__ unsigned bf16b(float x)   // f32 -> bf16 bits (RNE)
{
    unsigned u = __float_as_uint(x);
    return (u + 0x7fffu + ((u >> 16) & 1u)) >> 16;
}

template<int ND>
__device__ __forceinline__ void band_core(
    const float* __restrict__ f1base,          // f1 + (b*256 + cq*128)*4096 + lane
    const unsigned (* __restrict__ sw)[72],    // this wave's 64 padded channel-pair rows
    int ty, int dy0, int lane,
    float acc[3][PATCH])
{
    int yoff[ND];                          // clamped; invalid rows discarded at merge
#pragma unroll
    for (int i = 0; i < ND; ++i) {
        int y = ty + dy0 + i - MD;
        y = y < 0 ? 0 : (y > 63 ? 63 : y);
        yoff[i] = y * 64;
    }

#pragma unroll 2
    for (int cp = 0; cp < 64; ++cp) {      // channel pair: channels 2cp, 2cp+1 of this half
        const float* c0 = f1base + (size_t)(2 * cp) * 4096;
        float f1v0[ND], f1v1[ND];
#pragma unroll
        for (int i = 0; i < ND; ++i) {
            f1v0[i] = c0[yoff[i]];                    // batched coalesced global loads
            f1v1[i] = c0[4096 + yoff[i]];
        }
        const unsigned* wp = &sw[cp][lane];
        unsigned sh2[PATCH];
#pragma unroll
        for (int dxi = 0; dxi < PATCH; ++dxi)
            sh2[dxi] = wp[8 - dxi];                   // ds_read_b32: 2 channels per read
#pragma unroll
        for (int dxi = 0; dxi < PATCH; ++dxi) {
            float lo = __uint_as_float(sh2[dxi] << 16);          // channel 2cp
            float hi = __uint_as_float(sh2[dxi] & 0xffff0000u);  // channel 2cp+1
#pragma unroll
            for (int i = 0; i < ND; ++i) {
                acc[i][dxi] = fmaf(f1v0[i], lo, acc[i][dxi]);
                acc[i][dxi] = fmaf(f1v1[i], hi, acc[i][dxi]);
            }
        }
    }
}

__global__ __launch_bounds__(BT, 8) void cv_kernel(
    const float* __restrict__ f1,
    const float* __restrict__ f2,
    float* __restrict__ out)
{
    const int tid = threadIdx.x;

    // ---------------- zero-streaming blocks ----------------
    if (blockIdx.x >= NBAND) {
        // float4 index i: bits [0:4)=x4, [4:10)=y, [10:16)=tx, [16:22)=ty, [22:24)=b
        float* o = (float*)out;
        const int total4 = 4 * 4096 * 64 * 16;            // 16,777,216
        const int stride = NZERO * BT;
        for (int i = (blockIdx.x - NBAND) * BT + tid; i < total4; i += stride) {
            int y  = (i >> 4) & 63;
            int ty = (i >> 16) & 63;
            int dy = y - ty;
            if (dy < -MD || dy > MD)
                nt_store4(o + (size_t)i * 4, 0.f, 0.f, 0.f, 0.f);
        }
        return;
    }

    // ---------------- band-compute blocks ----------------
    // XCD swizzle: with round-robin block->XCD dispatch, XCD k gets 32 CONSECUTIVE bty
    // -> its L2 keeps the shared f1 row window. (Wrong mapping costs nothing.)
    const int bid = blockIdx.x;       // 0..255
    const int bty = ((bid & 7) << 5) | (bid >> 3);
    const int b   = bty >> 6;
    const int ty  = bty & 63;
    const int lane = tid & 63;        // u = x position
    const int w    = tid >> 6;        // 0..7
    const int cq   = w >> 2;          // channel half (128 ch each)
    const int dyg  = w & 3;           // dy group: rows {0,1}/{2,3}/{4,5}/{6,7,8}
    const int dy0  = dyg * 2;
    const int nd   = (dyg == 3) ? 3 : 2;

    __shared__ unsigned uLds[128 * 72];    // 36,864 B: sF2[128][72] u32-pairs, sVals after
    unsigned (*sF2)[72] = (unsigned(*)[72])uLds;

    // zero the 4-slot margins: p in {0,1,2,3,68,69,70,71} per pair-row
    for (int i = tid; i < 128 * 8; i += BT) {
        int c2 = i >> 3, s = i & 7;
        sF2[c2][s < 4 ? s : 64 + s] = 0u;
    }
    // main staging: e -> c2 = e>>6 (pair row), x = e&63; coalesced f32 reads, u32 writes
    const float* f2b = f2 + (size_t)(b * 256) * 4096 + ty * 64;
#pragma unroll
    for (int m = 0; m < 16; ++m) {
        int e  = m * BT + tid;        // 0..8191
        int c2 = e >> 6, x = e & 63;
        float lo = f2b[(size_t)(2 * c2) * 4096 + x];
        float hi = f2b[(size_t)(2 * c2 + 1) * 4096 + x];
        sF2[c2][4 + x] = (bf16b(hi) << 16) | bf16b(lo);
    }
    __syncthreads();

    float acc[3][PATCH];
#pragma unroll
    for (int i = 0; i < 3; ++i)
#pragma unroll
        for (int j = 0; j < PATCH; ++j) acc[i][j] = 0.f;

    const float* f1b = f1 + (size_t)(b * 256 + cq * 128) * 4096 + lane;
    const unsigned (*sw)[72] = &sF2[cq * 64];

    if (dyg == 3) band_core<3>(f1b, sw, ty, dy0, lane, acc);
    else          band_core<2>(f1b, sw, ty, dy0, lane, acc);

    __syncthreads();                  // all sF2 reads complete; uLds becomes sVals
    float (*sVals)[81] = (float(*)[81])uLds;   // sVals[tx][dyi*9+dxi]

    // Merge without zero-fill: cq==0 waves cover every read entry exactly once -> store.
    if (cq == 0) {
#pragma unroll
        for (int i = 0; i < 3; ++i) {
            if (i >= nd) continue;    // wave-uniform
            int dyi = dy0 + i;
            int y = ty + dyi - MD;
            if ((unsigned)y >= 64u) continue;
#pragma unroll
            for (int dxi = 0; dxi < PATCH; ++dxi) {
                int tx = lane - (dxi - MD);
                if ((unsigned)tx < 64u)
                    sVals[tx][dyi * PATCH + dxi] = acc[i][dxi];   // stride 81: conflict-free
            }
        }
    }
    __syncthreads();
    if (cq != 0) {
#pragma unroll
        for (int i = 0; i < 3; ++i) {
            if (i >= nd) continue;
            int dyi = dy0 + i;
            int y = ty + dyi - MD;
            if ((unsigned)y >= 64u) continue;
#pragma unroll
            for (int dxi = 0; dxi < PATCH; ++dxi) {
                int tx = lane - (dxi - MD);
                if ((unsigned)tx < 64u)
                    atomicAdd(&sVals[tx][dyi * PATCH + dxi], acc[i][dxi]);
            }
        }
    }
    __syncthreads();

    // Band rows: full 64-float rows (9-wide value window, zeros elsewhere). NT stores.
    float* outb = out + (size_t)(b * 4096 + ty * 64) * 4096;
    const int q4 = tid & 15;          // float4 index within a row
    const int ro = tid >> 4;          // 0..31
    for (int rb = 0; rb < 64 * PATCH; rb += 32) {
        int row = rb + ro;            // row = tx*9 + dyi
        int tx  = row / PATCH;        // const divisor -> magic multiply
        int dyi = row - tx * PATCH;
        int y   = ty + dyi - MD;
        if ((unsigned)y < 64u) {
            float comp[4];
#pragma unroll
            for (int j = 0; j < 4; ++j) {
                int x  = q4 * 4 + j;
                int dx = x - tx;
                comp[j] = (dx >= -MD && dx <= MD) ? sVals[tx][dyi * PATCH + dx + MD] : 0.f;
            }
            nt_store4(outb + (size_t)tx * 4096 + y * 64 + q4 * 4,
                      comp[0], comp[1], comp[2], comp[3]);
        }
    }
}

extern "C" void kernel_launch(void* const* d_in, const int* in_sizes, int n_in,
                              void* d_out, int out_size, void* d_ws, size_t ws_size,
                              hipStream_t stream) {
    const float* f1 = (const float*)d_in[0];
    const float* f2 = (const float*)d_in[1];
    float* out = (float*)d_out;
    cv_kernel<<<NBAND + NZERO, BT, 0, stream>>>(f1, f2, out);
}